// Round 8
// baseline (3769.983 us; speedup 1.0000x reference)
//
#include <hip/hip_runtime.h>

// ---------------------------------------------------------------------------
// LSTM (B=128, T=512, D=512, H=1024, O=256), forget bias 1.0
//   r8 = r7 with the nontemporal-builtin type fix (ext_vector f32x4 instead
//   of HIP_vector_type float4 in conv).
//   r7: r6 structure + NON-TEMPORAL streaming (nt) for xw loads, bulk output
//   stores, and GEMM C-writes, so the small coherent exchange set (teamh +
//   flags) stays Infinity-Cache-resident instead of being flushed by the
//   536MB xw stream. Exchange protocol unchanged from r6.
// ---------------------------------------------------------------------------

typedef _Float16 f16;
typedef _Float16 half8 __attribute__((ext_vector_type(8)));
typedef float floatx4 __attribute__((ext_vector_type(4)));
typedef float f32x4 __attribute__((ext_vector_type(4)));
typedef unsigned u32x4 __attribute__((ext_vector_type(4)));

#define AS1 __attribute__((address_space(1)))
#define AS3 __attribute__((address_space(3)))

__device__ __forceinline__ void gload_lds16(const void* g, void* l) {
  __builtin_amdgcn_global_load_lds((const AS1 void*)g, (AS3 void*)l, 16, 0, 0);
}
// coherent (device-scope) variant: aux = SC0|SC1 = 1|16
__device__ __forceinline__ void gload_lds16_coh(const void* g, void* l) {
  __builtin_amdgcn_global_load_lds((const AS1 void*)g, (AS3 void*)l, 16, 0, 17);
}
__device__ __forceinline__ void store_flag_coh(unsigned* p, unsigned v) {
  asm volatile("global_store_dword %0, %1, off sc0 sc1" :: "v"(p), "v"(v) : "memory");
}
__device__ __forceinline__ void store_h_coh(f16* p, f16 v) {
  unsigned uv = (unsigned)__builtin_bit_cast(unsigned short, v);
  asm volatile("global_store_short %0, %1, off sc0 sc1" :: "v"(p), "v"(uv) : "memory");
}
__device__ __forceinline__ u32x4 load_flag4_coh(const unsigned* p) {
  u32x4 v;
  asm volatile("global_load_dwordx4 %0, %1, off sc0 sc1\n\ts_waitcnt vmcnt(0)"
               : "=v"(v) : "v"(p) : "memory");
  return v;
}

__device__ __forceinline__ float sigm(float x) { return 1.f / (1.f + __expf(-x)); }
__device__ __forceinline__ float tanh_fast(float x) {
  float ax = fabsf(x);
  float e = __expf(2.f * ax);          // overflows to +inf for big |x| -> t=1 exactly
  float t = 1.f - 2.f / (e + 1.f);
  return copysignf(t, x);
}

// ---------------- workspace layout ----------------
static constexpr size_t XW_OFF  = 0;
static constexpr size_t XW_BY   = (size_t)65536 * 4096 * 2;        // 536870912
static constexpr size_t L16_OFF = XW_OFF + XW_BY;                  // lstm_out f16 (aliases in16)
static constexpr size_t L16_BY  = (size_t)65536 * 1024 * 2;        // 134217728
static constexpr size_t IN16_OFF = L16_OFF;                        // inputs f16 (phase1 only)
static constexpr size_t WXT_OFF = L16_OFF + L16_BY;
static constexpr size_t WXT_BY  = (size_t)4096 * 512 * 2;
static constexpr size_t WOT_OFF = WXT_OFF + WXT_BY;
static constexpr size_t WOT_BY  = (size_t)256 * 1024 * 2;
static constexpr size_t WPK_OFF = WOT_OFF + WOT_BY;
static constexpr size_t WPK_BY  = (size_t)524288 * 8 * 2;          // W_h frag-packed
static constexpr size_t TH_OFF  = WPK_OFF + WPK_BY;
static constexpr size_t TH_BY   = (size_t)8 * 2 * 16 * 1024 * 2;   // h ping-pong per team
static constexpr size_t FLG_OFF = TH_OFF + TH_BY;
static constexpr size_t FLG_BY  = (size_t)8 * 256 * 4;             // flags[team][cb][wave]
static constexpr size_t WS_NEED = FLG_OFF + FLG_BY;

// ---------------- prep kernels ----------------
__global__ __launch_bounds__(256) void conv_f32_to_f16(const float* __restrict__ in,
                                                       f16* __restrict__ out) {
  size_t i = (size_t)blockIdx.x * 256 + threadIdx.x;
  const f32x4* in4 = (const f32x4*)in;
  f32x4 a = __builtin_nontemporal_load(in4 + i * 2);
  f32x4 b = __builtin_nontemporal_load(in4 + i * 2 + 1);
  half8 v = {(f16)a.x, (f16)a.y, (f16)a.z, (f16)a.w,
             (f16)b.x, (f16)b.y, (f16)b.z, (f16)b.w};
  __builtin_nontemporal_store(v, (half8*)(out + i * 8));
}

// out[c][r] = (f16)in[r][c]; grid = (C/64, R/64)
__global__ __launch_bounds__(256) void transpose_f32_to_f16(const float* __restrict__ in,
                                                            f16* __restrict__ out,
                                                            int R, int C) {
  __shared__ float tile[64][65];
  int tx = threadIdx.x & 63, ty = threadIdx.x >> 6;
  int c0 = blockIdx.x * 64, r0 = blockIdx.y * 64;
#pragma unroll
  for (int q = 0; q < 16; ++q) {
    int r = q * 4 + ty;
    tile[r][tx] = in[(size_t)(r0 + r) * C + c0 + tx];
  }
  __syncthreads();
#pragma unroll
  for (int q = 0; q < 16; ++q) {
    int oc = q * 4 + ty;
    out[(size_t)(c0 + oc) * R + r0 + tx] = (f16)tile[tx][oc];
  }
}

// Pack W_h (rows 512..1535 of W_lstm) as phase-2 MFMA A-operand fragments.
// m-map: m = lane&15 -> unit_local ul = m>>2, gate g = m&3; k = (lane>>4)*8+e.
__global__ __launch_bounds__(256) void pack_wh(const float* __restrict__ W,
                                               f16* __restrict__ wpack) {
  int s = blockIdx.x * 256 + threadIdx.x;   // 0 .. 524287
  int lane = s & 63;
  int ks = (s >> 6) & 31;
  int wv = (s >> 11) & 7;
  int cb = s >> 14;                          // 0..31
  int m = lane & 15;
  int ul = m >> 2, g = m & 3;
  int ncol = g * 1024 + cb * 32 + wv * 4 + ul;
  int kb = ks * 32 + (lane >> 4) * 8;
  half8 v;
#pragma unroll
  for (int e = 0; e < 8; ++e)
    v[e] = (f16)W[(size_t)(512 + kb + e) * 4096 + ncol];
  ((half8*)wpack)[s] = v;
}

// ---------------- generic f16 MFMA GEMM: C = A[MxK] * Bt[NxK]^T + bias ----------------
template <typename OT>
__global__ __launch_bounds__(256) void gemm_f16(const f16* __restrict__ A,
                                                const f16* __restrict__ Bt,
                                                const float* __restrict__ bias,
                                                OT* __restrict__ C,
                                                int M, int N, int K) {
  __shared__ __align__(16) char smem[32768];   // As 16K | Bs 16K
  const int tid = threadIdx.x;
  const int n0 = blockIdx.x * 128, m0 = blockIdx.y * 128;
  const int l = tid & 63, w = tid >> 6;
  const int wr = w >> 1, wc = w & 1;
  const int r16 = l & 15, hi = l >> 4;
  floatx4 acc[4][4];
#pragma unroll
  for (int a = 0; a < 4; ++a)
#pragma unroll
    for (int b = 0; b < 4; ++b) acc[a][b] = (floatx4){0.f, 0.f, 0.f, 0.f};

  const int nk = K >> 6;
  for (int kk = 0; kk < nk; ++kk) {
    __syncthreads();
#pragma unroll
    for (int q = 0; q < 4; ++q) {
      int c = q * 256 + tid;
      int row = c >> 3, g8 = c & 7;
      gload_lds16(A + (size_t)(m0 + row) * K + kk * 64 + g8 * 8, smem + c * 16);
    }
#pragma unroll
    for (int q = 0; q < 4; ++q) {
      int c = q * 256 + tid;
      int row = c >> 3, g8 = c & 7;
      gload_lds16(Bt + (size_t)(n0 + row) * K + kk * 64 + g8 * 8, smem + 16384 + c * 16);
    }
    __syncthreads();
#pragma unroll
    for (int ks = 0; ks < 2; ++ks) {
      half8 af[4], bf[4];
#pragma unroll
      for (int mi = 0; mi < 4; ++mi)
        af[mi] = *(const half8*)(smem + ((wr * 64 + mi * 16 + r16) * 64 + ks * 32 + hi * 8) * 2);
#pragma unroll
      for (int ni = 0; ni < 4; ++ni)
        bf[ni] = *(const half8*)(smem + 16384 +
                                 ((wc * 64 + ni * 16 + r16) * 64 + ks * 32 + hi * 8) * 2);
#pragma unroll
      for (int mi = 0; mi < 4; ++mi)
#pragma unroll
        for (int ni = 0; ni < 4; ++ni)
          acc[mi][ni] = __builtin_amdgcn_mfma_f32_16x16x32_f16(af[mi], bf[ni], acc[mi][ni], 0, 0, 0);
    }
  }
#pragma unroll
  for (int ni = 0; ni < 4; ++ni) {
    int col = n0 + wc * 64 + ni * 16 + r16;
    float bv = bias[col];
#pragma unroll
    for (int mi = 0; mi < 4; ++mi)
#pragma unroll
      for (int rr = 0; rr < 4; ++rr) {
        int row = m0 + wr * 64 + mi * 16 + hi * 4 + rr;
        __builtin_nontemporal_store((OT)(acc[mi][ni][rr] + bv), C + (size_t)row * N + col);
      }
  }
}

// ---------------- phase 2: persistent recurrent kernel ----------------
// grid 256 x 512. block bk: team = bk>>5 (16 batch rows), cb = bk&31 (units
// u0..u0+31). wave w: units u0 + w*4 .. +3, full K=1024.
// MFMA per lane: acc regs = 4 gates of (unit = u0+w*4+(l>>4), batch = b0+(l&15)).
// h LDS [16 rows][128 granules], granule swizzle p = logical ^ (row&7).
__global__ __launch_bounds__(512, 1)
void lstm_phase2(const f16* __restrict__ wpack, const f16* __restrict__ xw,
                 const float* __restrict__ c_in, const float* __restrict__ h_in,
                 const int* __restrict__ seq_lens,
                 f16* teamh_all, unsigned* flags,
                 float* __restrict__ lstm_out, f16* __restrict__ lstm16,
                 float* __restrict__ c_out, float* __restrict__ h_out) {
  __shared__ __align__(16) char smem[34816];   // h 32K | tile 16x34 f16 (1088B)
  const int tid = threadIdx.x;
  const int bk = blockIdx.x;
  const int team = bk >> 5, cb = bk & 31;
  const int b0 = team * 16;
  const int u0 = cb * 32;
  const int l = tid & 63, w = tid >> 6;
  const int r16 = l & 15, hi = l >> 4;

  // persistent W fragments (A-operand), 32 x half8 = 128 VGPRs
  half8 wf[32];
  {
    const half8* wp = (const half8*)wpack;
    size_t base = (size_t)(cb * 8 + w) * 32 * 64;
#pragma unroll
    for (int k = 0; k < 32; ++k) wf[k] = wp[base + (size_t)k * 64 + l];
  }

  // compute identity
  const int bc = b0 + r16;              // batch row
  const int uloc = w * 4 + hi;          // block-local unit 0..31
  const int uc = u0 + uloc;             // hidden unit
  float creg = c_in[bc * 1024 + uc];
  float hreg = h_in[bc * 1024 + uc];
  const int slen_c = seq_lens[bc];
  const f16* xwb = xw + ((size_t)bc * 512) * 4096 + uc;

  // reader (batch-major) identity for publish/bulk
  const int b_r = tid >> 5, u_r = tid & 31;
  const int slen_r = seq_lens[b0 + b_r];
  f16* tile = (f16*)(smem + 32768);     // [16][34] f16, pad vs bank conflicts

  f16* teamh = teamh_all + (size_t)team * 32768;      // 2 bufs x 16x1024
  unsigned* tflags = flags + team * 256;
  unsigned* wflag = tflags + cb * 8 + w;
  const unsigned* pollp = tflags + l * 4;

#pragma unroll 1
  for (int t = 0; t < 512; ++t) {
    const int rb = t & 1, wb = rb ^ 1;
    f16 xw0, xw1, xw2, xw3;
    const f16* xp = xwb + (size_t)t * 4096;

    if (t > 0) {
      if (w != 0) {                    // issue xw (nt) during wave0's poll
        xw0 = __builtin_nontemporal_load(xp);
        xw1 = __builtin_nontemporal_load(xp + 1024);
        xw2 = __builtin_nontemporal_load(xp + 2048);
        xw3 = __builtin_nontemporal_load(xp + 3072);
      } else {                         // wave0: ONLY flag loads outstanding
        while (true) {
          u32x4 v = load_flag4_coh(pollp);
          bool ok = (int)v.x >= t && (int)v.y >= t && (int)v.z >= t && (int)v.w >= t;
          if (__all(ok)) break;
          __builtin_amdgcn_s_sleep(1);
        }
      }
      __syncthreads();                 // bar P: h(t) published team-wide
      const char* hb = (const char*)(teamh + (size_t)rb * 16384);
#pragma unroll
      for (int q = 0; q < 4; ++q) {
        int G = q * 512 + tid, r = G >> 7, p = G & 127, dg = p ^ (r & 7);
        gload_lds16_coh(hb + (size_t)(r * 1024 + dg * 8) * 2, smem + G * 16);
      }
      if (w == 0) {
        xw0 = __builtin_nontemporal_load(xp);
        xw1 = __builtin_nontemporal_load(xp + 1024);
        xw2 = __builtin_nontemporal_load(xp + 2048);
        xw3 = __builtin_nontemporal_load(xp + 3072);
      }
    } else {
      xw0 = __builtin_nontemporal_load(xp);
      xw1 = __builtin_nontemporal_load(xp + 1024);
      xw2 = __builtin_nontemporal_load(xp + 2048);
      xw3 = __builtin_nontemporal_load(xp + 3072);
#pragma unroll
      for (int q = 0; q < 4; ++q) {
        int G = q * 512 + tid, r = G >> 7, p = G & 127, dg = p ^ (r & 7);
        const float* s = h_in + (size_t)(b0 + r) * 1024 + dg * 8;
        half8 v;
#pragma unroll
        for (int e = 0; e < 8; ++e) v[e] = (f16)s[e];
        *(half8*)(smem + G * 16) = v;
      }
    }
    __syncthreads();                   // bar D: h staged (drains gload + xw)

    // 32 MFMA over K=1024, 4 independent chains of 8
    floatx4 a0 = {0.f,0.f,0.f,0.f}, a1 = a0, a2 = a0, a3 = a0;
    const int sw = l & 7;
#pragma unroll
    for (int k = 0; k < 8; ++k) {
#define FR(K) (*(const half8*)(smem + r16 * 2048 + ((((K) * 4 + hi) ^ sw) * 16)))
      a0 = __builtin_amdgcn_mfma_f32_16x16x32_f16(wf[k],      FR(k),      a0, 0, 0, 0);
      a1 = __builtin_amdgcn_mfma_f32_16x16x32_f16(wf[8 + k],  FR(8 + k),  a1, 0, 0, 0);
      a2 = __builtin_amdgcn_mfma_f32_16x16x32_f16(wf[16 + k], FR(16 + k), a2, 0, 0, 0);
      a3 = __builtin_amdgcn_mfma_f32_16x16x32_f16(wf[24 + k], FR(24 + k), a3, 0, 0, 0);
#undef FR
    }
    floatx4 sacc = (a0 + a1) + (a2 + a3);   // acc[g]: g = i,j,f,o

    float gi = sacc[0] + (float)xw0;
    float gj = sacc[1] + (float)xw1;
    float gf = sacc[2] + (float)xw2;
    float go = sacc[3] + (float)xw3;
    float nc = creg * sigm(gf + 1.f) + sigm(gi) * tanh_fast(gj);
    float nhv = tanh_fast(nc) * sigm(go);
    if (t < slen_c) { creg = nc; hreg = nhv; }
    tile[r16 * 34 + uloc] = (f16)hreg;  // carried h -> batch-major transpose
    __syncthreads();                    // bar H

    // batch-major epilogue: bulk nt stores + coherent publish + per-wave flag
    f16 v16 = tile[b_r * 34 + u_r];
    bool valid_r = t < slen_r;
    size_t orow = ((size_t)(b0 + b_r) * 512 + t) * 1024 + u0 + u_r;
    __builtin_nontemporal_store(valid_r ? (float)v16 : 0.f, lstm_out + orow);
    __builtin_nontemporal_store(valid_r ? v16 : (f16)0, lstm16 + orow);
    store_h_coh(teamh + (size_t)wb * 16384 + b_r * 1024 + u0 + u_r, v16);
    asm volatile("s_waitcnt vmcnt(0)" ::: "memory");   // all this wave's stores acked
    if (l == 0) store_flag_coh(wflag, (unsigned)(t + 1));
  }

  c_out[bc * 1024 + uc] = creg;
  h_out[bc * 1024 + uc] = hreg;
}

// ---------------- host ----------------
extern "C" void kernel_launch(void* const* d_in, const int* in_sizes, int n_in,
                              void* d_out, int out_size, void* d_ws, size_t ws_size,
                              hipStream_t stream) {
  const float* inputs  = (const float*)d_in[0];
  const float* c_in    = (const float*)d_in[1];
  const float* h_in    = (const float*)d_in[2];
  const float* W_lstm  = (const float*)d_in[3];
  const float* b_lstm  = (const float*)d_in[4];
  const float* W_out   = (const float*)d_in[5];
  const float* b_out   = (const float*)d_in[6];
  const int*   seq_lens= (const int*)d_in[7];

  float* logits  = (float*)d_out;
  float* lstm_out= logits + (size_t)65536 * 256;
  float* c_out   = lstm_out + (size_t)65536 * 1024;
  float* h_out   = c_out + (size_t)128 * 1024;

  if (ws_size < WS_NEED) return;   // fail visibly (poison stays) rather than corrupt

  char* ws = (char*)d_ws;
  f16* xw    = (f16*)(ws + XW_OFF);
  f16* in16  = (f16*)(ws + IN16_OFF);
  f16* l16   = (f16*)(ws + L16_OFF);
  f16* wxt   = (f16*)(ws + WXT_OFF);
  f16* wot   = (f16*)(ws + WOT_OFF);
  f16* wpk   = (f16*)(ws + WPK_OFF);
  f16* teamh = (f16*)(ws + TH_OFF);
  unsigned* flags = (unsigned*)(ws + FLG_OFF);

  hipMemsetAsync(flags, 0, FLG_BY, stream);
  conv_f32_to_f16<<<16384, 256, 0, stream>>>(inputs, in16);
  transpose_f32_to_f16<<<dim3(64, 8), 256, 0, stream>>>(W_lstm, wxt, 512, 4096);
  transpose_f32_to_f16<<<dim3(4, 16), 256, 0, stream>>>(W_out, wot, 1024, 256);
  pack_wh<<<2048, 256, 0, stream>>>(W_lstm, wpk);

  // phase 1: xw = X @ W_x + b_lstm
  gemm_f16<f16><<<dim3(32, 512), 256, 0, stream>>>(in16, wxt, b_lstm, xw, 65536, 4096, 512);

  // phase 2: persistent recurrence (cooperative => co-residency guaranteed)
  {
    const f16* wpk_c = wpk;
    const f16* xw_c  = xw;
    void* args[] = {(void*)&wpk_c, (void*)&xw_c, (void*)&c_in, (void*)&h_in,
                    (void*)&seq_lens, (void*)&teamh, (void*)&flags,
                    (void*)&lstm_out, (void*)&l16, (void*)&c_out, (void*)&h_out};
    hipLaunchCooperativeKernel((void*)lstm_phase2, dim3(256), dim3(512), args, 0, stream);
  }

  // phase 3: logits = lstm_out @ W_out + b_out
  gemm_f16<float><<<dim3(2, 512), 256, 0, stream>>>(l16, wot, b_out, logits, 65536, 256, 1024);
}

// Round 10
// 2671.249 us; speedup vs baseline: 1.4113x; 1.4113x over previous
//
#include <hip/hip_runtime.h>

// ---------------------------------------------------------------------------
// LSTM (B=128, T=512, D=512, H=1024, O=256), forget bias 1.0
//   r10 = merge of the two best measured components:
//   - r2 exchange protocol (fastest measured, 1843us): block-wide publish
//     (h stores sc0sc1 -> vmcnt(0) -> block barrier -> ONE flag store by
//     tid0), wave0 polls the team's 32 block-flags. Poll now uses 8
//     dwordx4 loads (8 IF$ transactions/iter vs 32).
//   - r6 compute core: swapped-operand MFMA (lane holds all 4 gates of one
//     (unit,batch) in its 4 acc regs) -> no LDS reduction phase.
//   Bulk lstm_out/lstm16 stores moved AFTER the flag store (off the chain).
//   All r8 nt-hints and r9 XCD-rendezvous reverted (r8: +traffic; r9: hang).
// ---------------------------------------------------------------------------

typedef _Float16 f16;
typedef _Float16 half8 __attribute__((ext_vector_type(8)));
typedef float floatx4 __attribute__((ext_vector_type(4)));
typedef float f32x4 __attribute__((ext_vector_type(4)));
typedef unsigned u32x4 __attribute__((ext_vector_type(4)));

#define AS1 __attribute__((address_space(1)))
#define AS3 __attribute__((address_space(3)))

__device__ __forceinline__ void gload_lds16(const void* g, void* l) {
  __builtin_amdgcn_global_load_lds((const AS1 void*)g, (AS3 void*)l, 16, 0, 0);
}
// device-coherent (IF$) staging: aux = SC0|SC1 = 17
__device__ __forceinline__ void gload_lds16_coh(const void* g, void* l) {
  __builtin_amdgcn_global_load_lds((const AS1 void*)g, (AS3 void*)l, 16, 0, 17);
}
__device__ __forceinline__ void store_flag_coh(unsigned* p, unsigned v) {
  asm volatile("global_store_dword %0, %1, off sc0 sc1" :: "v"(p), "v"(v) : "memory");
}
__device__ __forceinline__ void store_h_coh(f16* p, f16 v) {
  unsigned uv = (unsigned)__builtin_bit_cast(unsigned short, v);
  asm volatile("global_store_short %0, %1, off sc0 sc1" :: "v"(p), "v"(uv) : "memory");
}
__device__ __forceinline__ u32x4 load_flag4_coh(const unsigned* p) {
  u32x4 v;
  asm volatile("global_load_dwordx4 %0, %1, off sc0 sc1\n\ts_waitcnt vmcnt(0)"
               : "=v"(v) : "v"(p) : "memory");
  return v;
}

__device__ __forceinline__ float sigm(float x) { return 1.f / (1.f + __expf(-x)); }
__device__ __forceinline__ float tanh_fast(float x) {
  float ax = fabsf(x);
  float e = __expf(2.f * ax);          // overflows to +inf for big |x| -> t=1 exactly
  float t = 1.f - 2.f / (e + 1.f);
  return copysignf(t, x);
}

// ---------------- workspace layout ----------------
static constexpr size_t XW_OFF  = 0;
static constexpr size_t XW_BY   = (size_t)65536 * 4096 * 2;        // 536870912
static constexpr size_t L16_OFF = XW_OFF + XW_BY;                  // lstm_out f16 (aliases in16)
static constexpr size_t L16_BY  = (size_t)65536 * 1024 * 2;        // 134217728
static constexpr size_t IN16_OFF = L16_OFF;                        // inputs f16 (phase1 only)
static constexpr size_t WXT_OFF = L16_OFF + L16_BY;
static constexpr size_t WXT_BY  = (size_t)4096 * 512 * 2;
static constexpr size_t WOT_OFF = WXT_OFF + WXT_BY;
static constexpr size_t WOT_BY  = (size_t)256 * 1024 * 2;
static constexpr size_t WPK_OFF = WOT_OFF + WOT_BY;
static constexpr size_t WPK_BY  = (size_t)524288 * 8 * 2;          // W_h frag-packed
static constexpr size_t TH_OFF  = WPK_OFF + WPK_BY;
static constexpr size_t TH_BY   = (size_t)8 * 2 * 16 * 1024 * 2;   // h ping-pong per team
static constexpr size_t FLG_OFF = TH_OFF + TH_BY;
static constexpr size_t FLG_BY  = (size_t)8 * 32 * 4;              // flags[team][cb]
static constexpr size_t WS_NEED = FLG_OFF + FLG_BY;

// ---------------- prep kernels ----------------
__global__ __launch_bounds__(256) void conv_f32_to_f16(const float* __restrict__ in,
                                                       f16* __restrict__ out) {
  size_t i = (size_t)blockIdx.x * 256 + threadIdx.x;
  const f32x4* in4 = (const f32x4*)in;
  f32x4 a = in4[i * 2], b = in4[i * 2 + 1];
  half8 v = {(f16)a.x, (f16)a.y, (f16)a.z, (f16)a.w,
             (f16)b.x, (f16)b.y, (f16)b.z, (f16)b.w};
  *(half8*)(out + i * 8) = v;
}

// out[c][r] = (f16)in[r][c]; grid = (C/64, R/64)
__global__ __launch_bounds__(256) void transpose_f32_to_f16(const float* __restrict__ in,
                                                            f16* __restrict__ out,
                                                            int R, int C) {
  __shared__ float tile[64][65];
  int tx = threadIdx.x & 63, ty = threadIdx.x >> 6;
  int c0 = blockIdx.x * 64, r0 = blockIdx.y * 64;
#pragma unroll
  for (int q = 0; q < 16; ++q) {
    int r = q * 4 + ty;
    tile[r][tx] = in[(size_t)(r0 + r) * C + c0 + tx];
  }
  __syncthreads();
#pragma unroll
  for (int q = 0; q < 16; ++q) {
    int oc = q * 4 + ty;
    out[(size_t)(c0 + oc) * R + r0 + tx] = (f16)tile[tx][oc];
  }
}

// Pack W_h (rows 512..1535 of W_lstm) as phase-2 MFMA A-operand fragments.
// m-map: m = lane&15 -> unit_local ul = m>>2, gate g = m&3; k = (lane>>4)*8+e.
__global__ __launch_bounds__(256) void pack_wh(const float* __restrict__ W,
                                               f16* __restrict__ wpack) {
  int s = blockIdx.x * 256 + threadIdx.x;   // 0 .. 524287
  int lane = s & 63;
  int ks = (s >> 6) & 31;
  int wv = (s >> 11) & 7;
  int cb = s >> 14;                          // 0..31
  int m = lane & 15;
  int ul = m >> 2, g = m & 3;
  int ncol = g * 1024 + cb * 32 + wv * 4 + ul;
  int kb = ks * 32 + (lane >> 4) * 8;
  half8 v;
#pragma unroll
  for (int e = 0; e < 8; ++e)
    v[e] = (f16)W[(size_t)(512 + kb + e) * 4096 + ncol];
  ((half8*)wpack)[s] = v;
}

// ---------------- generic f16 MFMA GEMM: C = A[MxK] * Bt[NxK]^T + bias ----------------
template <typename OT>
__global__ __launch_bounds__(256) void gemm_f16(const f16* __restrict__ A,
                                                const f16* __restrict__ Bt,
                                                const float* __restrict__ bias,
                                                OT* __restrict__ C,
                                                int M, int N, int K) {
  __shared__ __align__(16) char smem[32768];   // As 16K | Bs 16K
  const int tid = threadIdx.x;
  const int n0 = blockIdx.x * 128, m0 = blockIdx.y * 128;
  const int l = tid & 63, w = tid >> 6;
  const int wr = w >> 1, wc = w & 1;
  const int r16 = l & 15, hi = l >> 4;
  floatx4 acc[4][4];
#pragma unroll
  for (int a = 0; a < 4; ++a)
#pragma unroll
    for (int b = 0; b < 4; ++b) acc[a][b] = (floatx4){0.f, 0.f, 0.f, 0.f};

  const int nk = K >> 6;
  for (int kk = 0; kk < nk; ++kk) {
    __syncthreads();
#pragma unroll
    for (int q = 0; q < 4; ++q) {
      int c = q * 256 + tid;
      int row = c >> 3, g8 = c & 7;
      gload_lds16(A + (size_t)(m0 + row) * K + kk * 64 + g8 * 8, smem + c * 16);
    }
#pragma unroll
    for (int q = 0; q < 4; ++q) {
      int c = q * 256 + tid;
      int row = c >> 3, g8 = c & 7;
      gload_lds16(Bt + (size_t)(n0 + row) * K + kk * 64 + g8 * 8, smem + 16384 + c * 16);
    }
    __syncthreads();
#pragma unroll
    for (int ks = 0; ks < 2; ++ks) {
      half8 af[4], bf[4];
#pragma unroll
      for (int mi = 0; mi < 4; ++mi)
        af[mi] = *(const half8*)(smem + ((wr * 64 + mi * 16 + r16) * 64 + ks * 32 + hi * 8) * 2);
#pragma unroll
      for (int ni = 0; ni < 4; ++ni)
        bf[ni] = *(const half8*)(smem + 16384 +
                                 ((wc * 64 + ni * 16 + r16) * 64 + ks * 32 + hi * 8) * 2);
#pragma unroll
      for (int mi = 0; mi < 4; ++mi)
#pragma unroll
        for (int ni = 0; ni < 4; ++ni)
          acc[mi][ni] = __builtin_amdgcn_mfma_f32_16x16x32_f16(af[mi], bf[ni], acc[mi][ni], 0, 0, 0);
    }
  }
#pragma unroll
  for (int ni = 0; ni < 4; ++ni) {
    int col = n0 + wc * 64 + ni * 16 + r16;
    float bv = bias[col];
#pragma unroll
    for (int mi = 0; mi < 4; ++mi)
#pragma unroll
      for (int rr = 0; rr < 4; ++rr) {
        int row = m0 + wr * 64 + mi * 16 + hi * 4 + rr;
        C[(size_t)row * N + col] = (OT)(acc[mi][ni][rr] + bv);
      }
  }
}

// ---------------- phase 2: persistent recurrent kernel ----------------
// grid 256 x 512. block bk: team = bk>>5 (16 batch rows), cb = bk&31 (units
// u0..u0+31). wave w: units u0 + w*4 .. +3, full K=1024.
// MFMA per lane: acc regs = 4 gates of (unit = u0+w*4+(l>>4), batch = b0+(l&15)).
// h LDS [16 rows][128 granules], granule swizzle p = logical ^ (row&7).
__global__ __launch_bounds__(512, 1)
void lstm_phase2(const f16* __restrict__ wpack, const f16* __restrict__ xw,
                 const float* __restrict__ c_in, const float* __restrict__ h_in,
                 const int* __restrict__ seq_lens,
                 f16* teamh_all, unsigned* flags,
                 float* __restrict__ lstm_out, f16* __restrict__ lstm16,
                 float* __restrict__ c_out, float* __restrict__ h_out) {
  __shared__ __align__(16) char smem[34816];   // h 32K | tile 16x34 f16
  const int tid = threadIdx.x;
  const int bk = blockIdx.x;
  const int team = bk >> 5, cb = bk & 31;
  const int b0 = team * 16;
  const int u0 = cb * 32;
  const int l = tid & 63, w = tid >> 6;
  const int r16 = l & 15, hi = l >> 4;

  // persistent W fragments (A-operand), 32 x half8 = 128 VGPRs
  half8 wf[32];
  {
    const half8* wp = (const half8*)wpack;
    size_t base = (size_t)(cb * 8 + w) * 32 * 64;
#pragma unroll
    for (int k = 0; k < 32; ++k) wf[k] = wp[base + (size_t)k * 64 + l];
  }

  // compute identity
  const int bc = b0 + r16;              // batch row
  const int uloc = w * 4 + hi;          // block-local unit 0..31
  const int uc = u0 + uloc;             // hidden unit
  float creg = c_in[bc * 1024 + uc];
  float hreg = h_in[bc * 1024 + uc];
  const int slen_c = seq_lens[bc];
  const f16* xwb = xw + ((size_t)bc * 512) * 4096 + uc;

  // reader (batch-major) identity for publish/bulk
  const int b_r = tid >> 5, u_r = tid & 31;
  const int slen_r = seq_lens[b0 + b_r];
  f16* tile = (f16*)(smem + 32768);     // [16][34] f16

  f16* teamh = teamh_all + (size_t)team * 32768;      // 2 bufs x 16x1024
  unsigned* tflags = flags + team * 32;
  unsigned* bflag = tflags + cb;        // this block's single flag
  const unsigned* pollp = tflags + (l & 7) * 4;   // 8 dwordx4 granules cover 32 flags

#pragma unroll 1
  for (int t = 0; t < 512; ++t) {
    const int rb = t & 1, wb = rb ^ 1;
    f16 xw0, xw1, xw2, xw3;
    const f16* xp = xwb + (size_t)t * 4096;

    if (t > 0) {
      if (w != 0) {                    // issue xw (cached) during wave0's poll
        xw0 = xp[0]; xw1 = xp[1024]; xw2 = xp[2048]; xw3 = xp[3072];
      } else {                         // wave0: poll 32 flags via 8 dwordx4
        while (true) {
          u32x4 v = load_flag4_coh(pollp);
          bool ok = (int)v.x >= t && (int)v.y >= t && (int)v.z >= t && (int)v.w >= t;
          if (__all(ok)) break;
          __builtin_amdgcn_s_sleep(1);
        }
      }
      __syncthreads();                 // bar P: h(t) published team-wide
      const char* hb = (const char*)(teamh + (size_t)rb * 16384);
#pragma unroll
      for (int q = 0; q < 4; ++q) {
        int G = q * 512 + tid, r = G >> 7, p = G & 127, dg = p ^ (r & 7);
        gload_lds16_coh(hb + (size_t)(r * 1024 + dg * 8) * 2, smem + G * 16);
      }
      if (w == 0) { xw0 = xp[0]; xw1 = xp[1024]; xw2 = xp[2048]; xw3 = xp[3072]; }
    } else {
      xw0 = xp[0]; xw1 = xp[1024]; xw2 = xp[2048]; xw3 = xp[3072];
#pragma unroll
      for (int q = 0; q < 4; ++q) {
        int G = q * 512 + tid, r = G >> 7, p = G & 127, dg = p ^ (r & 7);
        const float* s = h_in + (size_t)(b0 + r) * 1024 + dg * 8;
        half8 v;
#pragma unroll
        for (int e = 0; e < 8; ++e) v[e] = (f16)s[e];
        *(half8*)(smem + G * 16) = v;
      }
    }
    __syncthreads();                   // bar D: h staged (drains gload + xw)

    // 32 MFMA over K=1024, 4 independent chains of 8
    floatx4 a0 = {0.f,0.f,0.f,0.f}, a1 = a0, a2 = a0, a3 = a0;
    const int sw = l & 7;
#pragma unroll
    for (int k = 0; k < 8; ++k) {
#define FR(K) (*(const half8*)(smem + r16 * 2048 + ((((K) * 4 + hi) ^ sw) * 16)))
      a0 = __builtin_amdgcn_mfma_f32_16x16x32_f16(wf[k],      FR(k),      a0, 0, 0, 0);
      a1 = __builtin_amdgcn_mfma_f32_16x16x32_f16(wf[8 + k],  FR(8 + k),  a1, 0, 0, 0);
      a2 = __builtin_amdgcn_mfma_f32_16x16x32_f16(wf[16 + k], FR(16 + k), a2, 0, 0, 0);
      a3 = __builtin_amdgcn_mfma_f32_16x16x32_f16(wf[24 + k], FR(24 + k), a3, 0, 0, 0);
#undef FR
    }
    floatx4 sacc = (a0 + a1) + (a2 + a3);   // acc[g]: g = i,j,f,o

    float gi = sacc[0] + (float)xw0;
    float gj = sacc[1] + (float)xw1;
    float gf = sacc[2] + (float)xw2;
    float go = sacc[3] + (float)xw3;
    float nc = creg * sigm(gf + 1.f) + sigm(gi) * tanh_fast(gj);
    float nhv = tanh_fast(nc) * sigm(go);
    if (t < slen_c) { creg = nc; hreg = nhv; }
    tile[r16 * 34 + uloc] = (f16)hreg;  // carried h -> batch-major transpose
    __syncthreads();                    // bar H

    // publish FIRST (critical chain), bulk stores after the flag
    f16 v16 = tile[b_r * 34 + u_r];
    store_h_coh(teamh + (size_t)wb * 16384 + b_r * 1024 + u0 + u_r, v16);
    asm volatile("s_waitcnt vmcnt(0)" ::: "memory");   // h stores acked at IF$
    __syncthreads();                    // bar Q: whole block's h committed
    if (tid == 0) store_flag_coh(bflag, (unsigned)(t + 1));

    bool valid_r = t < slen_r;
    size_t orow = ((size_t)(b0 + b_r) * 512 + t) * 1024 + u0 + u_r;
    lstm_out[orow] = valid_r ? (float)v16 : 0.f;
    lstm16[orow] = valid_r ? v16 : (f16)0;
  }

  c_out[bc * 1024 + uc] = creg;
  h_out[bc * 1024 + uc] = hreg;
}

// ---------------- host ----------------
extern "C" void kernel_launch(void* const* d_in, const int* in_sizes, int n_in,
                              void* d_out, int out_size, void* d_ws, size_t ws_size,
                              hipStream_t stream) {
  const float* inputs  = (const float*)d_in[0];
  const float* c_in    = (const float*)d_in[1];
  const float* h_in    = (const float*)d_in[2];
  const float* W_lstm  = (const float*)d_in[3];
  const float* b_lstm  = (const float*)d_in[4];
  const float* W_out   = (const float*)d_in[5];
  const float* b_out   = (const float*)d_in[6];
  const int*   seq_lens= (const int*)d_in[7];

  float* logits  = (float*)d_out;
  float* lstm_out= logits + (size_t)65536 * 256;
  float* c_out   = lstm_out + (size_t)65536 * 1024;
  float* h_out   = c_out + (size_t)128 * 1024;

  if (ws_size < WS_NEED) return;   // fail visibly (poison stays) rather than corrupt

  char* ws = (char*)d_ws;
  f16* xw    = (f16*)(ws + XW_OFF);
  f16* in16  = (f16*)(ws + IN16_OFF);
  f16* l16   = (f16*)(ws + L16_OFF);
  f16* wxt   = (f16*)(ws + WXT_OFF);
  f16* wot   = (f16*)(ws + WOT_OFF);
  f16* wpk   = (f16*)(ws + WPK_OFF);
  f16* teamh = (f16*)(ws + TH_OFF);
  unsigned* flags = (unsigned*)(ws + FLG_OFF);

  hipMemsetAsync(flags, 0, FLG_BY, stream);
  conv_f32_to_f16<<<16384, 256, 0, stream>>>(inputs, in16);
  transpose_f32_to_f16<<<dim3(64, 8), 256, 0, stream>>>(W_lstm, wxt, 512, 4096);
  transpose_f32_to_f16<<<dim3(4, 16), 256, 0, stream>>>(W_out, wot, 1024, 256);
  pack_wh<<<2048, 256, 0, stream>>>(W_lstm, wpk);

  // phase 1: xw = X @ W_x + b_lstm
  gemm_f16<f16><<<dim3(32, 512), 256, 0, stream>>>(in16, wxt, b_lstm, xw, 65536, 4096, 512);

  // phase 2: persistent recurrence (cooperative => co-residency guaranteed)
  {
    const f16* wpk_c = wpk;
    const f16* xw_c  = xw;
    void* args[] = {(void*)&wpk_c, (void*)&xw_c, (void*)&c_in, (void*)&h_in,
                    (void*)&seq_lens, (void*)&teamh, (void*)&flags,
                    (void*)&lstm_out, (void*)&l16, (void*)&c_out, (void*)&h_out};
    hipLaunchCooperativeKernel((void*)lstm_phase2, dim3(256), dim3(512), args, 0, stream);
  }

  // phase 3: logits = lstm_out @ W_out + b_out
  gemm_f16<float><<<dim3(2, 512), 256, 0, stream>>>(l16, wot, b_out, logits, 65536, 256, 1024);
}